// Round 9
// baseline (3275.140 us; speedup 1.0000x reference)
//
#include <hip/hip_runtime.h>
#include <math.h>

#define MM_GELU 1
#define MM_RES 2
#define MM_SPLIT 4
#define MM_SPLITONLY 8
#define MM_LNA 16

typedef __attribute__((ext_vector_type(8))) short bfrag;
typedef __attribute__((ext_vector_type(4))) float f32x4;

__device__ inline unsigned short f2bf_rne(float f) {
  unsigned u = __float_as_uint(f);
  unsigned r = u + 0x7FFFu + ((u >> 16) & 1u);
  return (unsigned short)(r >> 16);
}
__device__ inline float bf2f(unsigned short h) {
  return __uint_as_float(((unsigned)h) << 16);
}

// ---------------- embedding + positional encoding ----------------
__global__ __launch_bounds__(128) void embed_kernel(
    const int* __restrict__ xm, const int* __restrict__ xa,
    const int* __restrict__ xh, const int* __restrict__ xw,
    const float* __restrict__ em, const float* __restrict__ ea,
    const float* __restrict__ eh, const float* __restrict__ ew,
    float* __restrict__ x1, float* __restrict__ x2) {
  int row = blockIdx.x;
  int d = threadIdx.x;
  int s = row % 1000;
  float v;
  if (d < 64)       v = em[xm[row]*64 + d];
  else if (d < 96)  v = ea[xa[row]*32 + (d-64)];
  else if (d < 112) v = eh[xh[row]*16 + (d-96)];
  else              v = ew[xw[row]*16 + (d-112)];
  int i = d >> 1;
  float dv = expf((float)(2*i) * (-9.21034037198f/128.f));
  float ang = (float)s * dv;
  v += (d & 1) ? cosf(ang) : sinf(ang);
  x1[row*128 + d] = v;
  x2[row*128 + d] = v;
}

// ---------------- layernorm (final norm only) -> bf16 hi/lo ----------------
__global__ __launch_bounds__(256) void ln_kernel(
    const float* __restrict__ x, const float* __restrict__ xb,
    const float* __restrict__ g, const float* __restrict__ b,
    unsigned short* __restrict__ oh, unsigned short* __restrict__ ol) {
  int row = blockIdx.x * 4 + (threadIdx.x >> 6);
  int t = threadIdx.x & 63;
  float v0 = x[row*128 + t], v1 = x[row*128 + 64 + t];
  if (xb) { v0 = 0.5f*(v0 + xb[row*128 + t]); v1 = 0.5f*(v1 + xb[row*128 + 64 + t]); }
  float sum = v0 + v1;
  #pragma unroll
  for (int o = 32; o > 0; o >>= 1) sum += __shfl_xor(sum, o);
  float mean = sum * (1.f/128.f);
  float d0 = v0 - mean, d1 = v1 - mean;
  float vs = d0*d0 + d1*d1;
  #pragma unroll
  for (int o = 32; o > 0; o >>= 1) vs += __shfl_xor(vs, o);
  float rstd = rsqrtf(vs*(1.f/128.f) + 1e-5f);
  float y0 = d0*rstd*g[t]    + b[t];
  float y1 = d1*rstd*g[t+64] + b[t+64];
  unsigned short h0 = f2bf_rne(y0), h1 = f2bf_rne(y1);
  oh[row*128 + t]      = h0;
  ol[row*128 + t]      = f2bf_rne(y0 - bf2f(h0));
  oh[row*128 + 64 + t] = h1;
  ol[row*128 + 64 + t] = f2bf_rne(y1 - bf2f(h1));
}

// ---------------- one-time weight transpose + bf16 hi/lo split ----------------
__global__ __launch_bounds__(256) void splitT_kernel(
    const float* __restrict__ src, unsigned short* __restrict__ hiT,
    unsigned short* __restrict__ loT, int K, int N,
    long srcStride, long dstStride) {
  src += (size_t)blockIdx.z * srcStride;
  hiT += (size_t)blockIdx.z * dstStride;
  loT += (size_t)blockIdx.z * dstStride;
  int n0 = blockIdx.x * 64, k0 = blockIdx.y * 64;
  __shared__ unsigned short sH[64][68], sL[64][68];
  int tid = threadIdx.x;
  int c = tid & 63, r4 = tid >> 6;
  #pragma unroll
  for (int rr = 0; rr < 16; ++rr) {
    int r = r4 + rr*4;
    float val = (n0 + c < N) ? src[(size_t)(k0 + r)*N + n0 + c] : 0.f;
    unsigned short h = f2bf_rne(val);
    sH[r][c] = h;
    sL[r][c] = f2bf_rne(val - bf2f(h));
  }
  __syncthreads();
  #pragma unroll
  for (int rr = 0; rr < 16; ++rr) {
    int n = r4 + rr*4;
    if (n0 + n < N) {
      hiT[(size_t)(n0 + n)*K + k0 + c] = sH[c][n];
      loT[(size_t)(n0 + n)*K + k0 + c] = sL[c][n];
    }
  }
}

// ---------------- bf16x3 MFMA matmul; A pre-split OR f32+fused-LN ----------------
__global__ __launch_bounds__(256) void mm_bf16_kernel(
    const unsigned short* __restrict__ Ah, const unsigned short* __restrict__ Al,
    const float* __restrict__ Afp, const float* __restrict__ lnG, const float* __restrict__ lnB,
    const unsigned short* __restrict__ BhT, const unsigned short* __restrict__ BlT,
    const float* __restrict__ bias, float* __restrict__ C,
    unsigned short* __restrict__ Ch, unsigned short* __restrict__ Cl,
    int M, int N, int K, int lda, int flags) {
  __shared__ __align__(16) unsigned short sAh[64][72], sAl[64][72], sBh[64][72], sBl[64][72];
  __shared__ float MEAN[64], RSTD[64];
  int tid = threadIdx.x;
  int bm = blockIdx.x * 64, bn = blockIdx.y * 64;
  int w = tid >> 6, lane = tid & 63;
  int l15 = lane & 15, kg = lane >> 4;
  if (flags & MM_LNA) {
    // row stats prepass (K==128): 4 threads per row, 32 cols each
    int rr = tid >> 2, cq = (tid & 3) * 32;
    const float* ap = Afp + (size_t)(bm + rr)*lda + cq;
    float s = 0.f, s2 = 0.f;
    #pragma unroll
    for (int j = 0; j < 8; ++j) {
      float4 f = *(const float4*)(ap + j*4);
      s += f.x + f.y + f.z + f.w;
      s2 += f.x*f.x + f.y*f.y + f.z*f.z + f.w*f.w;
    }
    s += __shfl_xor(s, 1);  s += __shfl_xor(s, 2);
    s2 += __shfl_xor(s2, 1); s2 += __shfl_xor(s2, 2);
    float mean = s * (1.f/128.f);
    float var = s2 * (1.f/128.f) - mean*mean;
    if ((tid & 3) == 0) { MEAN[rr] = mean; RSTD[rr] = rsqrtf(var + 1e-5f); }
    __syncthreads();
  }
  f32x4 acc[4];
  #pragma unroll
  for (int t = 0; t < 4; ++t) { acc[t][0]=0.f; acc[t][1]=0.f; acc[t][2]=0.f; acc[t][3]=0.f; }

  for (int k0 = 0; k0 < K; k0 += 64) {
    #pragma unroll
    for (int uu = 0; uu < 2; ++uu) {
      int u = tid + uu*256;
      int rr = u >> 3, cc = u & 7;
      if (flags & MM_LNA) {
        int k = k0 + cc*8;
        const float* ap = Afp + (size_t)(bm + rr)*lda + k;
        float4 fa = *(const float4*)(ap);
        float4 fb = *(const float4*)(ap + 4);
        float av8[8] = {fa.x, fa.y, fa.z, fa.w, fb.x, fb.y, fb.z, fb.w};
        float mean = MEAN[rr], rstd = RSTD[rr];
        bfrag vh, vl;
        #pragma unroll
        for (int j = 0; j < 8; ++j) {
          float y = (av8[j] - mean)*rstd*lnG[k + j] + lnB[k + j];
          unsigned short h = f2bf_rne(y);
          vh[j] = (short)h;
          vl[j] = (short)f2bf_rne(y - bf2f(h));
        }
        *(bfrag*)&sAh[rr][cc*8] = vh;
        *(bfrag*)&sAl[rr][cc*8] = vl;
      } else {
        size_t ga = (size_t)(bm + rr)*lda + k0 + cc*8;
        *(bfrag*)&sAh[rr][cc*8] = *(const bfrag*)(Ah + ga);
        *(bfrag*)&sAl[rr][cc*8] = *(const bfrag*)(Al + ga);
      }
      int n = bn + rr;
      if (n < N) {
        size_t gb = (size_t)n*K + k0 + cc*8;
        *(bfrag*)&sBh[rr][cc*8] = *(const bfrag*)(BhT + gb);
        *(bfrag*)&sBl[rr][cc*8] = *(const bfrag*)(BlT + gb);
      } else {
        bfrag z = {0,0,0,0,0,0,0,0};
        *(bfrag*)&sBh[rr][cc*8] = z;
        *(bfrag*)&sBl[rr][cc*8] = z;
      }
    }
    __syncthreads();
    #pragma unroll
    for (int ks = 0; ks < 2; ++ks) {
      int am = w*16 + l15;
      bfrag a_h = *(const bfrag*)&sAh[am][ks*32 + kg*8];
      bfrag a_l = *(const bfrag*)&sAl[am][ks*32 + kg*8];
      #pragma unroll
      for (int t = 0; t < 4; ++t) {
        int nn = t*16 + l15;
        bfrag b_h = *(const bfrag*)&sBh[nn][ks*32 + kg*8];
        bfrag b_l = *(const bfrag*)&sBl[nn][ks*32 + kg*8];
        acc[t] = __builtin_amdgcn_mfma_f32_16x16x32_bf16(a_h, b_h, acc[t], 0, 0, 0);
        acc[t] = __builtin_amdgcn_mfma_f32_16x16x32_bf16(a_h, b_l, acc[t], 0, 0, 0);
        acc[t] = __builtin_amdgcn_mfma_f32_16x16x32_bf16(a_l, b_h, acc[t], 0, 0, 0);
      }
    }
    __syncthreads();
  }
  #pragma unroll
  for (int t = 0; t < 4; ++t) {
    int col = bn + t*16 + l15;
    if (col < N) {
      #pragma unroll
      for (int r = 0; r < 4; ++r) {
        int row = bm + w*16 + kg*4 + r;
        float val = acc[t][r];
        if (bias) val += bias[col];
        if (flags & MM_GELU) val = 0.5f*val*(1.f + erff(val*0.70710678118f));
        size_t oi;
        if (flags & MM_SPLIT) {
          int bb = row / 1000, ss = row % 1000;
          int hd = (col >> 4) & 7, dd = col & 15;
          oi = (((size_t)(bb*8 + hd))*1000 + ss)*16 + dd;
          if (col >= 128) oi += 2048000;     // vv plane (qkv fused)
        } else {
          oi = (size_t)row*N + col;
        }
        if (flags & MM_SPLITONLY) {
          unsigned short h = f2bf_rne(val);
          Ch[oi] = h;
          Cl[oi] = f2bf_rne(val - bf2f(h));
        } else if (flags & MM_RES) C[oi] += val;
        else C[oi] = val;
      }
    }
  }
}

// ---------------- fused LSH bucket + stable counting sort (barrier-free) ----------------
// grid 256 = 128 bh x 2 halves; block 128 = 2 waves, wave handles one round.
__global__ __launch_bounds__(128) void bucketsort_kernel(
    const float* __restrict__ qk, const float* __restrict__ rot,
    int* __restrict__ st, int* __restrict__ undo) {
  int bh = blockIdx.x >> 1;
  int wv = threadIdx.x >> 6;
  int r = (blockIdx.x & 1)*2 + wv;
  int lane = threadIdx.x & 63;
  __shared__ int bkt[2][1000];
  __shared__ int off[2][48];
  // bucket phase
  for (int s = lane; s < 1000; s += 64) {
    const float* qr = qk + ((size_t)bh*1000 + s)*16;
    float q[16];
    #pragma unroll
    for (int j = 0; j < 4; ++j) {
      float4 f = *(const float4*)(qr + j*4);
      q[j*4+0]=f.x; q[j*4+1]=f.y; q[j*4+2]=f.z; q[j*4+3]=f.w;
    }
    float rv[20];
    #pragma unroll
    for (int n = 0; n < 20; ++n) {
      float acc = 0.f;
      #pragma unroll
      for (int d = 0; d < 16; ++d) acc += q[d]*rot[(d*4 + r)*20 + n];
      rv[n] = acc;
    }
    float best = -INFINITY; int bi = 0;
    #pragma unroll
    for (int n = 0; n < 40; ++n) {
      float val = (n < 20) ? rv[n] : -rv[n-20];
      if (val > best) { best = val; bi = n; }
    }
    bkt[wv][s] = bi;
  }
  if (lane < 48) off[wv][lane] = 0;
  unsigned long long below = ((1ull << lane) - 1ull);
  // pass 1: counts
  for (int c = 0; c < 16; ++c) {
    int s = c*64 + lane;
    bool valid = (s < 1000);
    int b = valid ? bkt[wv][s] : 0;
    unsigned long long mask = __ballot(valid);
    #pragma unroll
    for (int bit = 0; bit < 6; ++bit) {
      unsigned long long vote = __ballot((b >> bit) & 1);
      mask &= ((b >> bit) & 1) ? vote : ~vote;
    }
    if (valid) {
      int rank = (int)__popcll(mask & below);
      if (rank == 0) off[wv][b] += (int)__popcll(mask);
    }
  }
  if (lane == 0) {
    int acc = 0;
    for (int bb = 0; bb < 40; ++bb) { int cn = off[wv][bb]; off[wv][bb] = acc; acc += cn; }
  }
  int base = bh*4000 + r*1000;
  // pass 2: stable placement
  for (int c = 0; c < 16; ++c) {
    int s = c*64 + lane;
    bool valid = (s < 1000);
    int b = valid ? bkt[wv][s] : 0;
    unsigned long long mask = __ballot(valid);
    #pragma unroll
    for (int bit = 0; bit < 6; ++bit) {
      unsigned long long vote = __ballot((b >> bit) & 1);
      mask &= ((b >> bit) & 1) ? vote : ~vote;
    }
    if (valid) {
      int myoff = off[wv][b];
      int rank = (int)__popcll(mask & below);
      int slot = myoff + rank;
      st[base + slot] = s;
      undo[base + s] = r*1000 + slot;
      if (rank == 0) off[wv][b] = myoff + (int)__popcll(mask);
    }
  }
}

// ---------------- per-chunk attention: 2 lanes per query, register softmax ----------------
__global__ __launch_bounds__(64) void attn_chunk_kernel(
    const float* __restrict__ qk, const float* __restrict__ v,
    const int* __restrict__ st, const int* __restrict__ xm,
    float* __restrict__ so, float* __restrict__ slse) {
  int blk = blockIdx.x;
  int bh = blk / 160;
  int n = blk % 160;
  int b = bh >> 3;
  int lane = threadIdx.x;
  __shared__ __align__(16) float RAW[50][20];
  __shared__ __align__(16) float BV[50][20];
  __shared__ float RSQ[50];
  __shared__ int TKV[50], MKV[50];
  int pn = (n + 159) % 160;
  if (lane < 50) {
    int slot = (lane < 25) ? (n*25 + lane) : (pn*25 + (lane - 25));
    int t = st[bh*4000 + slot];
    TKV[lane] = t;
    MKV[lane] = (xm[b*1000 + t] != 0) ? 1 : 0;
  }
  __syncthreads();
  for (int e = lane; e < 200; e += 64) {
    int rr = e >> 2, j = (e & 3) * 4;
    int t = TKV[rr];
    const float* qr = qk + ((size_t)bh*1000 + t)*16 + j;
    const float* vr = v  + ((size_t)bh*1000 + t)*16 + j;
    *(float4*)&RAW[rr][j] = *(const float4*)qr;
    *(float4*)&BV[rr][j]  = *(const float4*)vr;
  }
  __syncthreads();
  if (lane < 50) {
    float ss = 1e-9f;
    #pragma unroll
    for (int d = 0; d < 16; ++d) ss += RAW[lane][d]*RAW[lane][d];
    RSQ[lane] = rsqrtf(ss);
  }
  __syncthreads();
  if (lane < 50) {
    int q = lane % 25, h = lane / 25;
    int partner = (h == 0) ? lane + 25 : lane - 25;
    float sq[16];
    #pragma unroll
    for (int j = 0; j < 4; ++j) {
      float4 f = *(const float4*)&RAW[q][j*4];
      sq[j*4+0]=f.x; sq[j*4+1]=f.y; sq[j*4+2]=f.z; sq[j*4+3]=f.w;
    }
    int tq = TKV[q], mq = MKV[q];
    float p[25];
    #pragma unroll
    for (int i = 0; i < 25; ++i) {
      int k = h*25 + i;
      float acc = 0.f;
      #pragma unroll
      for (int j = 0; j < 4; ++j) {
        float4 f = *(const float4*)&RAW[k][j*4];
        acc += sq[j*4+0]*f.x + sq[j*4+1]*f.y + sq[j*4+2]*f.z + sq[j*4+3]*f.w;
      }
      acc *= 0.25f * RSQ[k];
      int tk = TKV[k], mk = MKV[k];
      if (!(mq && mk)) acc = -1e9f;
      if (tq < tk) acc = -1e9f;
      if (tq == tk) acc = -5e4f;
      p[i] = acc;
    }
    float m = -INFINITY;
    #pragma unroll
    for (int i = 0; i < 25; ++i) m = fmaxf(m, p[i]);
    m = fmaxf(m, __shfl(m, partner));
    float S = 0.f;
    #pragma unroll
    for (int i = 0; i < 25; ++i) { p[i] = expf(p[i] - m); S += p[i]; }
    S += __shfl(S, partner);
    float lse = m + logf(S);
    float rS = 1.f / S;
    float o[16];
    #pragma unroll
    for (int d = 0; d < 16; ++d) o[d] = 0.f;
    #pragma unroll
    for (int i = 0; i < 25; ++i) {
      int k = h*25 + i;
      float wt = p[i];
      #pragma unroll
      for (int j = 0; j < 4; ++j) {
        float4 f = *(const float4*)&BV[k][j*4];
        o[j*4+0] += wt*f.x; o[j*4+1] += wt*f.y; o[j*4+2] += wt*f.z; o[j*4+3] += wt*f.w;
      }
    }
    #pragma unroll
    for (int d = 0; d < 16; ++d) o[d] += __shfl(o[d], partner);
    if (h == 0) {
      int slot = n*25 + q;
      float* op = so + ((size_t)bh*4000 + slot)*16;
      #pragma unroll
      for (int j = 0; j < 4; ++j) {
        float4 f;
        f.x = o[j*4+0]*rS; f.y = o[j*4+1]*rS; f.z = o[j*4+2]*rS; f.w = o[j*4+3]*rS;
        *(float4*)(op + j*4) = f;
      }
      slse[bh*4000 + slot] = lse;
    }
  }
}

// ---------------- unsort + combine + merge heads -> bf16 hi/lo ----------------
__global__ __launch_bounds__(256) void combine_kernel(
    const float* __restrict__ so, const float* __restrict__ slse,
    const int* __restrict__ undo, unsigned short* __restrict__ aoh,
    unsigned short* __restrict__ aol) {
  int idx = blockIdx.x*256 + threadIdx.x;
  if (idx >= 2048000) return;
  int d = idx & 15;
  int s = (idx >> 4) % 1000;
  int bh = idx / 16000;
  int b = bh >> 3, hd = bh & 7;
  int s0 = undo[bh*4000 + s];
  int s1 = undo[bh*4000 + 1000 + s];
  int s2 = undo[bh*4000 + 2000 + s];
  int s3 = undo[bh*4000 + 3000 + s];
  float l0 = slse[bh*4000 + s0], l1 = slse[bh*4000 + s1];
  float l2 = slse[bh*4000 + s2], l3 = slse[bh*4000 + s3];
  float m = fmaxf(fmaxf(l0,l1), fmaxf(l2,l3));
  float w0 = expf(l0-m), w1 = expf(l1-m), w2 = expf(l2-m), w3 = expf(l3-m);
  float rs = 1.f/(w0+w1+w2+w3);
  const float* base = so + (size_t)bh*4000*16;
  float o = (w0*base[s0*16+d] + w1*base[s1*16+d] + w2*base[s2*16+d] + w3*base[s3*16+d]) * rs;
  size_t oi = ((size_t)b*1000 + s)*128 + hd*16 + d;
  unsigned short h = f2bf_rne(o);
  aoh[oi] = h;
  aol[oi] = f2bf_rne(o - bf2f(h));
}

// ---------------- PKM prep: M[k, (h,p,n)] ----------------
__global__ __launch_bounds__(256) void pkm_m_kernel(
    const float* __restrict__ Wq, const float* __restrict__ keys,
    float* __restrict__ M) {
  int hp = blockIdx.x;
  int h = hp >> 1, p = hp & 1;
  int tid = threadIdx.x;
  __shared__ float Ks[128][65];
  for (int e = tid; e < 8192; e += 256) {
    int n = e >> 6, d = e & 63;
    Ks[n][d] = keys[((size_t)(h*128 + n)*2 + p)*64 + d];
  }
  __syncthreads();
  int k = tid >> 1;
  int nbase = (tid & 1) * 64;
  float wk[64];
  const float* wq = Wq + (size_t)k*512 + h*128 + p*64;
  #pragma unroll
  for (int d = 0; d < 64; ++d) wk[d] = wq[d];
  for (int n = 0; n < 64; ++n) {
    int nn = nbase + n;
    float acc = 0.f;
    #pragma unroll
    for (int d = 0; d < 64; ++d) acc += wk[d]*Ks[nn][d];
    M[(size_t)k*1024 + hp*128 + nn] = acc;
  }
}

// ---------------- PKM select: ballot-bisection top-16 ----------------
__device__ inline unsigned long long pk_key(float v, int idx) {
  unsigned u = __float_as_uint(v);
  u = (u & 0x80000000u) ? ~u : (u | 0x80000000u);
  unsigned kv = ~u;
  return ((unsigned long long)kv << 32) | (unsigned)idx;
}
__device__ inline float pk_val(unsigned long long key) {
  unsigned m = ~(unsigned)(key >> 32);
  return (m & 0x80000000u) ? __uint_as_float(m & 0x7FFFFFFFu) : __uint_as_float(~m);
}
__device__ inline unsigned f32mono(float f) {
  unsigned u = __float_as_uint(f);
  return (u & 0x80000000u) ? ~u : (u | 0x80000000u);
}

__global__ __launch_bounds__(256) void pkm_select_kernel(
    const float* __restrict__ dots, const float* __restrict__ values,
    float* __restrict__ x2out) {
  int row = blockIdx.x;
  int tid = threadIdx.x;
  int h = tid >> 6;
  int lane = tid & 63;
  __shared__ unsigned long long STG[4][2][16];
  __shared__ float OUT[4][128];
  const float* dr = dots + (size_t)row*1024 + h*256;
  float vx0 = dr[lane], vx1 = dr[64 + lane];
  float vy0 = dr[128 + lane], vy1 = dr[192 + lane];
  unsigned mx0 = f32mono(vx0), mx1 = f32mono(vx1);
  unsigned my0 = f32mono(vy0), my1 = f32mono(vy1);
  unsigned long long below = ((1ull << lane) - 1ull);
  // ---- bisect 16th-largest threshold for x and y (interleaved chains) ----
  unsigned tx = 0, ty = 0;
  #pragma unroll
  for (int bit = 31; bit >= 0; --bit) {
    unsigned cx = tx | (1u << bit), cy = ty | (1u << bit);
    int nx = (int)(__popcll(__ballot(mx0 >= cx)) + __popcll(__ballot(mx1 >= cx)));
    int ny = (int)(__popcll(__ballot(my0 >= cy)) + __popcll(__ballot(my1 >= cy)));
    if (nx >= 16) tx = cx;
    if (ny >= 16) ty = cy;
  }
  // ---- compact exact top-16 of each segment (ties: lower idx) ----
  {
    unsigned long long g0 = __ballot(mx0 > tx), g1 = __ballot(mx1 > tx);
    unsigned long long e0 = __ballot(mx0 == tx), e1 = __ballot(mx1 == tx);
    int nGT = (int)(__popcll(g0) + __popcll(g1));
    int need = 16 - nGT;
    if (mx0 > tx) {
      STG[h][0][(int)__popcll(g0 & below)] = pk_key(vx0, lane);
    } else if (mx0 == tx) {
      int er = (int)__popcll(e0 & below);
      if (er < need) STG[h][0][nGT + er] = pk_key(vx0, lane);
    }
    if (mx1 > tx) {
      STG[h][0][(int)(__popcll(g0) + __popcll(g1 & below))] = pk_key(vx1, 64 + lane);
    } else if (mx1 == tx) {
      int er = (int)(__popcll(e0) + __popcll(e1 & below));
      if (er < need) STG[h][0][nGT + er] = pk_key(vx1, 64 + lane);
    }
  }
  {
    unsigned long long g0 = __ballot(my0 > ty), g1 = __ballot(my1 > ty);
    unsigned long long e0 = __ballot(my0 == ty), e1 = __ballot(my1 == ty);
    int nGT = (int)(__popcll(g0) + __popcll(g1));
    int need = 16 - nGT;
    if (my0 > ty) {
      STG[h][1][(int)__popcll(g0 & below)] = pk_key(vy0, lane);
    } else if (my0 == ty) {
      int er = (int)__popcll(e0 & below);
      if (er < need) STG[h][1][nGT + er] = pk_key(vy0, lane);
    }
    if (my1 > ty) {
      STG[h][1][(int)(__popcll(g0) + __popcll(g1 & below))] = pk_key(vy1, 64 + lane);
    } else if (my1 == ty) {
      int er = (int)(__popcll(e0) + __popcll(e1 & below));
      if (er < need) STG[h][1][nGT + er] = pk_key(vy1, 64 + lane);
    }
  }
  // ---- sort x-16 (lanes 0..15) and y-16 (lanes 16..31) concurrently ----
  unsigned long long skey = ~0ull;
  if (lane < 32) skey = STG[h][lane >> 4][lane & 15];
  int g16 = lane & 15;
  #pragma unroll
  for (int k = 2; k <= 16; k <<= 1) {
    #pragma unroll
    for (int j = k >> 1; j >= 1; j >>= 1) {
      unsigned long long pk2 = __shfl_xor(skey, j);
      bool low = ((g16 & j) == 0);
      bool up = ((g16 & k) == 0);
      bool take = (low == up) ? (pk2 < skey) : (pk2 > skey);
      if (take) skey = pk2;
    }
  }
  float sval = pk_val(skey);
  int sidx = (int)(unsigned)(skey & 0xFFFFFFFFull);
  // ---- staircase candidates (kx+1)(ky+1)<=16 ----
  int kx, ky;
  if      (lane < 16) { kx = 0; ky = lane; }
  else if (lane < 24) { kx = 1; ky = lane - 16; }
  else if (lane < 29) { kx = 2; ky = lane - 24; }
  else if (lane < 33) { kx = 3; ky = lane - 29; }
  else if (lane < 36) { kx = 4; ky = lane - 33; }
  else if (lane < 38) { kx = 5; ky = lane - 36; }
  else if (lane < 40) { kx = 6; ky = lane - 38; }
  else if (lane < 42) { kx = 7; ky = lane - 40; }
  else                { kx = 8 + (lane - 42); ky = 0; }
  float cval = __shfl(sval, kx) + __shfl(sval, 16 + ky);
  int cidx = kx*16 + ky;
  unsigned mc = (lane < 50) ? f32mono(cval) : 0u;
  // ---- bisect top-16 of 50 combos ----
  unsigned tc = 0;
  #pragma unroll
  for (int bit = 31; bit >= 0; --bit) {
    unsigned c = tc | (1u << bit);
    if ((int)__popcll(__ballot(mc >= c)) >= 16) tc = c;
  }
  {
    unsigned long long gt = __ballot(mc > tc), eq = __ballot(mc == tc);
    int nGT = (int)__popcll(gt);
    int need = 16 - nGT;
    if (mc > tc) {
      STG[h][0][(int)__popcll(gt & below)] = pk_key(cval, cidx);
    } else if (lane < 50 && mc == tc) {
      int er = (int)__popcll(eq & below);
      if (er < need) STG[h][0][nGT + er] = pk_key(cval, cidx);
    }
  }
  unsigned long long ck = (lane < 16) ? STG[h][0][lane] : ~0ull;
  #pragma unroll
  for (int k = 2; k <= 16; k <<= 1) {
    #pragma unroll
    for (int j = k >> 1; j >= 1; j >>= 1) {
      unsigned long long pk2 = __shfl_xor(ck, j);
      bool low = ((g16 & j) == 0);
      bool up = ((g16 & k) == 0);
      bool take = (low == up) ? (pk2 < ck) : (pk2 > ck);
      if (take) ck = pk2;
    }
  }
  float myv = pk_val(ck);
  int pos = (int)(ck & 0xFFull);
  int ix = __shfl(sidx, pos >> 4);
  int iy = __shfl(sidx, 16 + (pos & 15));
  int myfi = ix*128 + iy;
  float fs0 = __shfl(myv, 0);
  float osum0 = 0.f, osum1 = 0.f, wsum = 0.f;
  #pragma unroll
  for (int k = 0; k < 16; ++k) {
    float fv = __shfl(myv, k);
    int fik = __shfl(myfi, k);
    float wgk = expf(fv - fs0);
    wsum += wgk;
    const float* vr = values + (size_t)fik * 128;
    osum0 += wgk * vr[lane];
    osum1 += wgk * vr[lane + 64];
  }
  float rs = 1.f / wsum;
  OUT[h][lane] = osum0 * rs;
  OUT[h][lane + 64] = osum1 * rs;
  __syncthreads();
  if (tid < 128) {
    float r = OUT[0][tid] + OUT[1][tid] + OUT[2][tid] + OUT[3][tid];
    x2out[(size_t)row*128 + tid] += r;
  }
}

// ---------------- host ----------------
extern "C" void kernel_launch(void* const* d_in, const int* in_sizes, int n_in,
                              void* d_out, int out_size, void* d_ws, size_t ws_size,
                              hipStream_t stream) {
  (void)in_sizes; (void)n_in; (void)out_size; (void)ws_size;
  const int* x_mcc  = (const int*)d_in[0];
  const int* x_amt  = (const int*)d_in[1];
  const int* x_hour = (const int*)d_in[2];
  const int* x_wday = (const int*)d_in[3];
  const float* emb_mcc  = (const float*)d_in[4];
  const float* emb_amt  = (const float*)d_in[5];
  const float* emb_hour = (const float*)d_in[6];
  const float* emb_wday = (const float*)d_in[7];
  const float* rot   = (const float*)d_in[8];
  const float* ln1_g = (const float*)d_in[9];
  const float* ln1_b = (const float*)d_in[10];
  const float* ln2_g = (const float*)d_in[11];
  const float* ln2_b = (const float*)d_in[12];
  const float* Wqk = (const float*)d_in[13];
  const float* Wv  = (const float*)d_in[14];
  const float* Wo  = (const float*)d_in[15];
  const float* bo  = (const float*)d_in[16];
  const float* ff_w1 = (const float*)d_in[17];
  const float* ff_b1 = (const float*)d_in[18];
  const float* ff_w2 = (const float*)d_in[19];
  const float* ff_b2 = (const float*)d_in[20];
  const float* pkm_wq   = (const float*)d_in[21];
  const float* pkm_keys = (const float*)d_in[22];
  const float* pkm_vals = (const float*)d_in[23];
  const float* norm_g = (const float*)d_in[24];
  const float* norm_b = (const float*)d_in[25];
  const float* hw1 = (const float*)d_in[26];
  const float* hb1 = (const float*)d_in[27];

  float* ws = (float*)d_ws;
  float* x1v  = ws;
  float* x2v  = ws + 2048000;
  float* hbuf = ws + 4096000;              // final-ln bf16 hi/lo
  float* scrA = ws + 6144000;
  float* qk     = scrA;
  float* vv     = scrA + 2048000;
  float* so     = scrA + 4096000;
  float* slse   = scrA + 12288000;
  int*   stp    = (int*)(scrA + 13312000);
  int*   undo   = (int*)(scrA + 13824000);
  float* attn_o = scrA + 14336000;
  float* dotsb  = scrA;
  float* Mbuf   = ws + 22528000;

  unsigned short* hbuf_h = (unsigned short*)hbuf;
  unsigned short* hbuf_l = hbuf_h + 2048000;
  unsigned short* ao_h = (unsigned short*)attn_o;
  unsigned short* ao_l = ao_h + 2048000;
  unsigned short* big_h = (unsigned short*)scrA;     // [16000][512] (attn scratch dead)
  unsigned short* big_l = big_h + 8192000;

  unsigned short* wsp = (unsigned short*)(ws + 22700000);
  unsigned short* WqkvT_h = wsp;              // 8 x [256][128]
  unsigned short* WqkvT_l = wsp + 262144;
  unsigned short* WoT_h  = wsp + 524288;
  unsigned short* WoT_l  = wsp + 655360;
  unsigned short* f1T_h  = wsp + 786432;      // 6 x [512][128], 65536 each
  unsigned short* f1T_l  = wsp + 1179648;
  unsigned short* f2T_h  = wsp + 1572864;     // 6 x [128][512], 65536 each
  unsigned short* f2T_l  = wsp + 1966080;
  unsigned short* MT_h   = wsp + 2359296;     // [1024][128]
  unsigned short* MT_l   = wsp + 2490368;
  unsigned short* hw1T_h = wsp + 2621440;     // stacked [512][128]
  unsigned short* hw1T_l = wsp + 2686976;
  unsigned short* h2T_h  = wsp + 2752512;
  unsigned short* h2T_l  = wsp + 2814336;

  // ---- one-time weight splits ----
  { dim3 g(2,2,8); splitT_kernel<<<g,256,0,stream>>>(Wqk, WqkvT_h, WqkvT_l, 128,128, 16384, 32768); }
  { dim3 g(2,2,8); splitT_kernel<<<g,256,0,stream>>>(Wv,  WqkvT_h + 16384, WqkvT_l + 16384, 128,128, 16384, 32768); }
  { dim3 g(2,2,8); splitT_kernel<<<g,256,0,stream>>>(Wo,  WoT_h,  WoT_l,  128,128, 16384,16384); }
  { dim3 g(8,2,6); splitT_kernel<<<g,256,0,stream>>>(ff_w1, f1T_h, f1T_l, 128,512, 65536,65536); }
  { dim3 g(2,8,6); splitT_kernel<<<g,256,0,stream>>>(ff_w2, f2T_h, f2T_l, 512,128, 65536,65536); }
  { dim3 g(2,2,4); splitT_kernel<<<g,256,0,stream>>>(hw1, hw1T_h, hw1T_l, 128,128, 16384,16384); }
  const float* w2s[4] = {(const float*)d_in[28], (const float*)d_in[30], (const float*)d_in[32], (const float*)d_in[34]};
  const float* b2s[4] = {(const float*)d_in[29], (const float*)d_in[31], (const float*)d_in[33], (const float*)d_in[35]};
  const int ns[4] = {350, 100, 25, 8};
  const long h2off[4] = {0, 44800, 57600, 60800};
  for (int i = 0; i < 4; ++i) {
    dim3 g((ns[i]+63)/64, 2, 1);
    splitT_kernel<<<g,256,0,stream>>>(w2s[i], h2T_h + h2off[i], h2T_l + h2off[i], 128, ns[i], 0, 0);
  }

  embed_kernel<<<16000, 128, 0, stream>>>(x_mcc, x_amt, x_hour, x_wday,
      emb_mcc, emb_amt, emb_hour, emb_wday, x1v, x2v);

  int ffi = 0, pki = 0;
  for (int l = 0; l < 8; ++l) {
    // qkv: fused LN + [qk|vv] matmul
    { dim3 g(250, 4); mm_bf16_kernel<<<g, 256, 0, stream>>>(nullptr, nullptr, x2v, ln1_g + l*128, ln1_b + l*128,
        WqkvT_h + l*32768, WqkvT_l + l*32768, nullptr, qk, nullptr, nullptr, 16000, 256, 128, 128, MM_SPLIT|MM_LNA); }
    bucketsort_kernel<<<256, 128, 0, stream>>>(qk, rot, stp, undo);
    attn_chunk_kernel<<<20480, 64, 0, stream>>>(qk, vv, stp, x_mcc, so, slse);
    combine_kernel<<<8000, 256, 0, stream>>>(so, slse, undo, ao_h, ao_l);
    { dim3 g(250, 2); mm_bf16_kernel<<<g, 256, 0, stream>>>(ao_h, ao_l, nullptr, nullptr, nullptr,
        WoT_h + l*16384, WoT_l + l*16384, bo + l*128, x1v, nullptr, nullptr, 16000, 128, 128, 128, MM_RES); }
    if (l == 3 || l == 6) {
      pkm_m_kernel<<<8, 256, 0, stream>>>(pkm_wq + (size_t)pki*65536, pkm_keys + (size_t)pki*65536, Mbuf);
      { dim3 g(16, 2, 1); splitT_kernel<<<g,256,0,stream>>>(Mbuf, MT_h, MT_l, 128, 1024, 0, 0); }
      { dim3 g(250, 16); mm_bf16_kernel<<<g, 256, 0, stream>>>(nullptr, nullptr, x1v, ln2_g + l*128, ln2_b + l*128,
          MT_h, MT_l, nullptr, dotsb, nullptr, nullptr, 16000, 1024, 128, 128, MM_LNA); }
      pkm_select_kernel<<<16000, 256, 0, stream>>>(dotsb, pkm_vals + (size_t)pki*2097152, x2v);
      ++pki;
    } else {
      { dim3 g(250, 8); mm_bf16_kernel<<<g, 256, 0, stream>>>(nullptr, nullptr, x1v, ln2_g + l*128, ln2_b + l*128,
          f1T_h + ffi*65536, f1T_l + ffi*65536, ff_b1 + ffi*512, nullptr, big_h, big_l, 16000, 512, 128, 128, MM_GELU|MM_SPLITONLY|MM_LNA); }
      { dim3 g(250, 2); mm_bf16_kernel<<<g, 256, 0, stream>>>(big_h, big_l, nullptr, nullptr, nullptr,
          f2T_h + ffi*65536, f2T_l + ffi*65536, ff_b2 + ffi*128, x2v, nullptr, nullptr, 16000, 128, 512, 512, MM_RES); }
      ++ffi;
    }
  }
  ln_kernel<<<4000, 256, 0, stream>>>(x1v, x2v, norm_g, norm_b, hbuf_h, hbuf_l);

  float* out = (float*)d_out;
  // batched head hidden: one [16000,512] = gelu(hbuf @ hw1_stacked + hb1)
  { dim3 g(250, 8); mm_bf16_kernel<<<g, 256, 0, stream>>>(hbuf_h, hbuf_l, nullptr, nullptr, nullptr,
      hw1T_h, hw1T_l, hb1, nullptr, big_h, big_l, 16000, 512, 128, 128, MM_GELU|MM_SPLITONLY); }
  size_t ooff = 0;
  for (int i = 0; i < 4; ++i) {
    { dim3 g(250, (unsigned)((ns[i]+63)/64)); mm_bf16_kernel<<<g, 256, 0, stream>>>(big_h + i*128, big_l + i*128,
        nullptr, nullptr, nullptr, h2T_h + h2off[i], h2T_l + h2off[i], b2s[i], out + ooff, nullptr, nullptr,
        16000, ns[i], 128, 512, 0); }
    ooff += (size_t)16000 * ns[i];
  }
}

// Round 10
// 2260.704 us; speedup vs baseline: 1.4487x; 1.4487x over previous
//
#include <hip/hip_runtime.h>
#include <math.h>

#define MM_GELU 1
#define MM_RES 2
#define MM_SPLIT 4
#define MM_SPLITONLY 8
#define MM_LNA 16

typedef __attribute__((ext_vector_type(8))) short bfrag;
typedef __attribute__((ext_vector_type(4))) float f32x4;

__device__ inline unsigned short f2bf_rne(float f) {
  unsigned u = __float_as_uint(f);
  unsigned r = u + 0x7FFFu + ((u >> 16) & 1u);
  return (unsigned short)(r >> 16);
}
__device__ inline float bf2f(unsigned short h) {
  return __uint_as_float(((unsigned)h) << 16);
}

// ---------------- embedding + positional encoding ----------------
__global__ __launch_bounds__(128) void embed_kernel(
    const int* __restrict__ xm, const int* __restrict__ xa,
    const int* __restrict__ xh, const int* __restrict__ xw,
    const float* __restrict__ em, const float* __restrict__ ea,
    const float* __restrict__ eh, const float* __restrict__ ew,
    float* __restrict__ x1, float* __restrict__ x2) {
  int row = blockIdx.x;
  int d = threadIdx.x;
  int s = row % 1000;
  float v;
  if (d < 64)       v = em[xm[row]*64 + d];
  else if (d < 96)  v = ea[xa[row]*32 + (d-64)];
  else if (d < 112) v = eh[xh[row]*16 + (d-96)];
  else              v = ew[xw[row]*16 + (d-112)];
  int i = d >> 1;
  float dv = expf((float)(2*i) * (-9.21034037198f/128.f));
  float ang = (float)s * dv;
  v += (d & 1) ? cosf(ang) : sinf(ang);
  x1[row*128 + d] = v;
  x2[row*128 + d] = v;
}

// ---------------- layernorm (final norm only) -> bf16 hi/lo ----------------
__global__ __launch_bounds__(256) void ln_kernel(
    const float* __restrict__ x, const float* __restrict__ xb,
    const float* __restrict__ g, const float* __restrict__ b,
    unsigned short* __restrict__ oh, unsigned short* __restrict__ ol) {
  int row = blockIdx.x * 4 + (threadIdx.x >> 6);
  int t = threadIdx.x & 63;
  float v0 = x[row*128 + t], v1 = x[row*128 + 64 + t];
  if (xb) { v0 = 0.5f*(v0 + xb[row*128 + t]); v1 = 0.5f*(v1 + xb[row*128 + 64 + t]); }
  float sum = v0 + v1;
  #pragma unroll
  for (int o = 32; o > 0; o >>= 1) sum += __shfl_xor(sum, o);
  float mean = sum * (1.f/128.f);
  float d0 = v0 - mean, d1 = v1 - mean;
  float vs = d0*d0 + d1*d1;
  #pragma unroll
  for (int o = 32; o > 0; o >>= 1) vs += __shfl_xor(vs, o);
  float rstd = rsqrtf(vs*(1.f/128.f) + 1e-5f);
  float y0 = d0*rstd*g[t]    + b[t];
  float y1 = d1*rstd*g[t+64] + b[t+64];
  unsigned short h0 = f2bf_rne(y0), h1 = f2bf_rne(y1);
  oh[row*128 + t]      = h0;
  ol[row*128 + t]      = f2bf_rne(y0 - bf2f(h0));
  oh[row*128 + 64 + t] = h1;
  ol[row*128 + 64 + t] = f2bf_rne(y1 - bf2f(h1));
}

// ---------------- one-time weight transpose + bf16 hi/lo split ----------------
__global__ __launch_bounds__(256) void splitT_kernel(
    const float* __restrict__ src, unsigned short* __restrict__ hiT,
    unsigned short* __restrict__ loT, int K, int N,
    long srcStride, long dstStride) {
  src += (size_t)blockIdx.z * srcStride;
  hiT += (size_t)blockIdx.z * dstStride;
  loT += (size_t)blockIdx.z * dstStride;
  int n0 = blockIdx.x * 64, k0 = blockIdx.y * 64;
  __shared__ unsigned short sH[64][68], sL[64][68];
  int tid = threadIdx.x;
  int c = tid & 63, r4 = tid >> 6;
  #pragma unroll
  for (int rr = 0; rr < 16; ++rr) {
    int r = r4 + rr*4;
    float val = (n0 + c < N) ? src[(size_t)(k0 + r)*N + n0 + c] : 0.f;
    unsigned short h = f2bf_rne(val);
    sH[r][c] = h;
    sL[r][c] = f2bf_rne(val - bf2f(h));
  }
  __syncthreads();
  #pragma unroll
  for (int rr = 0; rr < 16; ++rr) {
    int n = r4 + rr*4;
    if (n0 + n < N) {
      hiT[(size_t)(n0 + n)*K + k0 + c] = sH[c][n];
      loT[(size_t)(n0 + n)*K + k0 + c] = sL[c][n];
    }
  }
}

// ---------------- bf16x3 MFMA matmul; A pre-split OR f32+fused-LN ----------------
__global__ __launch_bounds__(256) void mm_bf16_kernel(
    const unsigned short* __restrict__ Ah, const unsigned short* __restrict__ Al,
    const float* __restrict__ Afp, const float* __restrict__ lnG, const float* __restrict__ lnB,
    const unsigned short* __restrict__ BhT, const unsigned short* __restrict__ BlT,
    const float* __restrict__ bias, float* __restrict__ C,
    unsigned short* __restrict__ Ch, unsigned short* __restrict__ Cl,
    int M, int N, int K, int lda, int flags) {
  __shared__ __align__(16) unsigned short sAh[64][72], sAl[64][72], sBh[64][72], sBl[64][72];
  __shared__ float MEAN[64], RSTD[64];
  int tid = threadIdx.x;
  int bm = blockIdx.x * 64, bn = blockIdx.y * 64;
  int w = tid >> 6, lane = tid & 63;
  int l15 = lane & 15, kg = lane >> 4;
  if (flags & MM_LNA) {
    int rr = tid >> 2, cq = (tid & 3) * 32;
    const float* ap = Afp + (size_t)(bm + rr)*lda + cq;
    float s = 0.f, s2 = 0.f;
    #pragma unroll
    for (int j = 0; j < 8; ++j) {
      float4 f = *(const float4*)(ap + j*4);
      s += f.x + f.y + f.z + f.w;
      s2 += f.x*f.x + f.y*f.y + f.z*f.z + f.w*f.w;
    }
    s += __shfl_xor(s, 1);  s += __shfl_xor(s, 2);
    s2 += __shfl_xor(s2, 1); s2 += __shfl_xor(s2, 2);
    float mean = s * (1.f/128.f);
    float var = s2 * (1.f/128.f) - mean*mean;
    if ((tid & 3) == 0) { MEAN[rr] = mean; RSTD[rr] = rsqrtf(var + 1e-5f); }
    __syncthreads();
  }
  f32x4 acc[4];
  #pragma unroll
  for (int t = 0; t < 4; ++t) { acc[t][0]=0.f; acc[t][1]=0.f; acc[t][2]=0.f; acc[t][3]=0.f; }

  for (int k0 = 0; k0 < K; k0 += 64) {
    #pragma unroll
    for (int uu = 0; uu < 2; ++uu) {
      int u = tid + uu*256;
      int rr = u >> 3, cc = u & 7;
      if (flags & MM_LNA) {
        int k = k0 + cc*8;
        const float* ap = Afp + (size_t)(bm + rr)*lda + k;
        float4 fa = *(const float4*)(ap);
        float4 fb = *(const float4*)(ap + 4);
        float av8[8] = {fa.x, fa.y, fa.z, fa.w, fb.x, fb.y, fb.z, fb.w};
        float mean = MEAN[rr], rstd = RSTD[rr];
        bfrag vh, vl;
        #pragma unroll
        for (int j = 0; j < 8; ++j) {
          float y = (av8[j] - mean)*rstd*lnG[k + j] + lnB[k + j];
          unsigned short h = f2bf_rne(y);
          vh[j] = (short)h;
          vl[j] = (short)f2bf_rne(y - bf2f(h));
        }
        *(bfrag*)&sAh[rr][cc*8] = vh;
        *(bfrag*)&sAl[rr][cc*8] = vl;
      } else {
        size_t ga = (size_t)(bm + rr)*lda + k0 + cc*8;
        *(bfrag*)&sAh[rr][cc*8] = *(const bfrag*)(Ah + ga);
        *(bfrag*)&sAl[rr][cc*8] = *(const bfrag*)(Al + ga);
      }
      int n = bn + rr;
      if (n < N) {
        size_t gb = (size_t)n*K + k0 + cc*8;
        *(bfrag*)&sBh[rr][cc*8] = *(const bfrag*)(BhT + gb);
        *(bfrag*)&sBl[rr][cc*8] = *(const bfrag*)(BlT + gb);
      } else {
        bfrag z = {0,0,0,0,0,0,0,0};
        *(bfrag*)&sBh[rr][cc*8] = z;
        *(bfrag*)&sBl[rr][cc*8] = z;
      }
    }
    __syncthreads();
    #pragma unroll
    for (int ks = 0; ks < 2; ++ks) {
      int am = w*16 + l15;
      bfrag a_h = *(const bfrag*)&sAh[am][ks*32 + kg*8];
      bfrag a_l = *(const bfrag*)&sAl[am][ks*32 + kg*8];
      #pragma unroll
      for (int t = 0; t < 4; ++t) {
        int nn = t*16 + l15;
        bfrag b_h = *(const bfrag*)&sBh[nn][ks*32 + kg*8];
        bfrag b_l = *(const bfrag*)&sBl[nn][ks*32 + kg*8];
        acc[t] = __builtin_amdgcn_mfma_f32_16x16x32_bf16(a_h, b_h, acc[t], 0, 0, 0);
        acc[t] = __builtin_amdgcn_mfma_f32_16x16x32_bf16(a_h, b_l, acc[t], 0, 0, 0);
        acc[t] = __builtin_amdgcn_mfma_f32_16x16x32_bf16(a_l, b_h, acc[t], 0, 0, 0);
      }
    }
    __syncthreads();
  }
  #pragma unroll
  for (int t = 0; t < 4; ++t) {
    int col = bn + t*16 + l15;
    if (col < N) {
      #pragma unroll
      for (int r = 0; r < 4; ++r) {
        int row = bm + w*16 + kg*4 + r;
        float val = acc[t][r];
        if (bias) val += bias[col];
        if (flags & MM_GELU) val = 0.5f*val*(1.f + erff(val*0.70710678118f));
        size_t oi;
        if (flags & MM_SPLIT) {
          int bb = row / 1000, ss = row % 1000;
          int hd = (col >> 4) & 7, dd = col & 15;
          oi = (((size_t)(bb*8 + hd))*1000 + ss)*16 + dd;
          if (col >= 128) oi += 2048000;     // vv plane (qkv fused)
        } else {
          oi = (size_t)row*N + col;
        }
        if (flags & MM_SPLITONLY) {
          unsigned short h = f2bf_rne(val);
          Ch[oi] = h;
          Cl[oi] = f2bf_rne(val - bf2f(h));
        } else if (flags & MM_RES) C[oi] += val;
        else C[oi] = val;
      }
    }
  }
}

// ---------------- LSH bucket assignment (high-TLP, 4 rounds per thread) ----------------
__global__ __launch_bounds__(256) void bucket_kernel(
    const float* __restrict__ qk, const float* __restrict__ rot,
    int* __restrict__ buckets) {
  int idx = blockIdx.x*256 + threadIdx.x;
  if (idx >= 128000) return;
  int bh = idx / 1000, s = idx % 1000;
  float q[16];
  #pragma unroll
  for (int d = 0; d < 16; ++d) q[d] = qk[(bh*1000+s)*16 + d];
  #pragma unroll 1
  for (int r = 0; r < 4; ++r) {
    float rv[20];
    #pragma unroll
    for (int n = 0; n < 20; ++n) {
      float acc = 0.f;
      #pragma unroll
      for (int d = 0; d < 16; ++d) acc += q[d]*rot[(d*4 + r)*20 + n];
      rv[n] = acc;
    }
    float best = -INFINITY; int bi = 0;
    #pragma unroll
    for (int n = 0; n < 40; ++n) {
      float val = (n < 20) ? rv[n] : -rv[n-20];
      if (val > best) { best = val; bi = n; }
    }
    buckets[(bh*4 + r)*1000 + s] = bi;
  }
}

// ---------------- stable counting sort per (bh, round): bitwise-ballot ranks ----------------
__global__ __launch_bounds__(64) void sort_kernel(
    const int* __restrict__ buckets, int* __restrict__ st, int* __restrict__ undo) {
  int bh = blockIdx.x >> 2;
  int r = blockIdx.x & 3;
  const int* bkt = buckets + (bh*4 + r)*1000;
  __shared__ int off[40];
  int lane = threadIdx.x;
  if (lane < 40) off[lane] = 0;
  __syncthreads();
  unsigned long long below = (lane == 63) ? 0x7FFFFFFFFFFFFFFFull : ((1ull << lane) - 1ull);
  for (int c = 0; c < 16; ++c) {
    int s = c*64 + lane;
    bool valid = (s < 1000);
    int b = valid ? bkt[s] : 0;
    unsigned long long mask = __ballot(valid);
    #pragma unroll
    for (int bit = 0; bit < 6; ++bit) {
      unsigned long long vote = __ballot((b >> bit) & 1);
      mask &= ((b >> bit) & 1) ? vote : ~vote;
    }
    if (valid) {
      int rank = (int)__popcll(mask & below);
      if (rank == 0) off[b] += (int)__popcll(mask);
    }
    __syncthreads();
  }
  if (lane == 0) {
    int acc = 0;
    for (int bb = 0; bb < 40; ++bb) { int cn = off[bb]; off[bb] = acc; acc += cn; }
  }
  __syncthreads();
  int base = bh*4000 + r*1000;
  for (int c = 0; c < 16; ++c) {
    int s = c*64 + lane;
    bool valid = (s < 1000);
    int b = valid ? bkt[s] : 0;
    unsigned long long mask = __ballot(valid);
    #pragma unroll
    for (int bit = 0; bit < 6; ++bit) {
      unsigned long long vote = __ballot((b >> bit) & 1);
      mask &= ((b >> bit) & 1) ? vote : ~vote;
    }
    if (valid) {
      int myoff = off[b];
      int rank = (int)__popcll(mask & below);
      int slot = myoff + rank;
      st[base + slot] = s;
      undo[base + s] = r*1000 + slot;
      if (rank == 0) off[b] = myoff + (int)__popcll(mask);
    }
    __syncthreads();
  }
}

// ---------------- per-chunk attention: 2 lanes per query, register softmax ----------------
__global__ __launch_bounds__(64) void attn_chunk_kernel(
    const float* __restrict__ qk, const float* __restrict__ v,
    const int* __restrict__ st, const int* __restrict__ xm,
    float* __restrict__ so, float* __restrict__ slse) {
  int blk = blockIdx.x;
  int bh = blk / 160;
  int n = blk % 160;
  int b = bh >> 3;
  int lane = threadIdx.x;
  __shared__ __align__(16) float RAW[50][20];
  __shared__ __align__(16) float BV[50][20];
  __shared__ float RSQ[50];
  __shared__ int TKV[50], MKV[50];
  int pn = (n + 159) % 160;
  if (lane < 50) {
    int slot = (lane < 25) ? (n*25 + lane) : (pn*25 + (lane - 25));
    int t = st[bh*4000 + slot];
    TKV[lane] = t;
    MKV[lane] = (xm[b*1000 + t] != 0) ? 1 : 0;
  }
  __syncthreads();
  for (int e = lane; e < 200; e += 64) {
    int rr = e >> 2, j = (e & 3) * 4;
    int t = TKV[rr];
    const float* qr = qk + ((size_t)bh*1000 + t)*16 + j;
    const float* vr = v  + ((size_t)bh*1000 + t)*16 + j;
    *(float4*)&RAW[rr][j] = *(const float4*)qr;
    *(float4*)&BV[rr][j]  = *(const float4*)vr;
  }
  __syncthreads();
  if (lane < 50) {
    float ss = 1e-9f;
    #pragma unroll
    for (int d = 0; d < 16; ++d) ss += RAW[lane][d]*RAW[lane][d];
    RSQ[lane] = rsqrtf(ss);
  }
  __syncthreads();
  if (lane < 50) {
    int q = lane % 25, h = lane / 25;
    int partner = (h == 0) ? lane + 25 : lane - 25;
    float sq[16];
    #pragma unroll
    for (int j = 0; j < 4; ++j) {
      float4 f = *(const float4*)&RAW[q][j*4];
      sq[j*4+0]=f.x; sq[j*4+1]=f.y; sq[j*4+2]=f.z; sq[j*4+3]=f.w;
    }
    int tq = TKV[q], mq = MKV[q];
    float p[25];
    #pragma unroll
    for (int i = 0; i < 25; ++i) {
      int k = h*25 + i;
      float acc = 0.f;
      #pragma unroll
      for (int j = 0; j < 4; ++j) {
        float4 f = *(const float4*)&RAW[k][j*4];
        acc += sq[j*4+0]*f.x + sq[j*4+1]*f.y + sq[j*4+2]*f.z + sq[j*4+3]*f.w;
      }
      acc *= 0.25f * RSQ[k];
      int tk = TKV[k], mk = MKV[k];
      if (!(mq && mk)) acc = -1e9f;
      if (tq < tk) acc = -1e9f;
      if (tq == tk) acc = -5e4f;
      p[i] = acc;
    }
    float m = -INFINITY;
    #pragma unroll
    for (int i = 0; i < 25; ++i) m = fmaxf(m, p[i]);
    m = fmaxf(m, __shfl(m, partner));
    float S = 0.f;
    #pragma unroll
    for (int i = 0; i < 25; ++i) { p[i] = expf(p[i] - m); S += p[i]; }
    S += __shfl(S, partner);
    float lse = m + logf(S);
    float rS = 1.f / S;
    float o[16];
    #pragma unroll
    for (int d = 0; d < 16; ++d) o[d] = 0.f;
    #pragma unroll
    for (int i = 0; i < 25; ++i) {
      int k = h*25 + i;
      float wt = p[i];
      #pragma unroll
      for (int j = 0; j < 4; ++j) {
        float4 f = *(const float4*)&BV[k][j*4];
        o[j*4+0] += wt*f.x; o[j*4+1] += wt*f.y; o[j*4+2] += wt*f.z; o[j*4+3] += wt*f.w;
      }
    }
    #pragma unroll
    for (int d = 0; d < 16; ++d) o[d] += __shfl(o[d], partner);
    if (h == 0) {
      int slot = n*25 + q;
      float* op = so + ((size_t)bh*4000 + slot)*16;
      #pragma unroll
      for (int j = 0; j < 4; ++j) {
        float4 f;
        f.x = o[j*4+0]*rS; f.y = o[j*4+1]*rS; f.z = o[j*4+2]*rS; f.w = o[j*4+3]*rS;
        *(float4*)(op + j*4) = f;
      }
      slse[bh*4000 + slot] = lse;
    }
  }
}

// ---------------- unsort + combine + merge heads -> bf16 hi/lo ----------------
__global__ __launch_bounds__(256) void combine_kernel(
    const float* __restrict__ so, const float* __restrict__ slse,
    const int* __restrict__ undo, unsigned short* __restrict__ aoh,
    unsigned short* __restrict__ aol) {
  int idx = blockIdx.x*256 + threadIdx.x;
  if (idx >= 2048000) return;
  int d = idx & 15;
  int s = (idx >> 4) % 1000;
  int bh = idx / 16000;
  int b = bh >> 3, hd = bh & 7;
  int s0 = undo[bh*4000 + s];
  int s1 = undo[bh*4000 + 1000 + s];
  int s2 = undo[bh*4000 + 2000 + s];
  int s3 = undo[bh*4000 + 3000 + s];
  float l0 = slse[bh*4000 + s0], l1 = slse[bh*4000 + s1];
  float l2 = slse[bh*4000 + s2], l3 = slse[bh*4000 + s3];
  float m = fmaxf(fmaxf(l0,l1), fmaxf(l2,l3));
  float w0 = expf(l0-m), w1 = expf(l1-m), w2 = expf(l2-m), w3 = expf(l3-m);
  float rs = 1.f/(w0+w1+w2+w3);
  const float* base = so + (size_t)bh*4000*16;
  float o = (w0*base[s0*16+d] + w1*base[s1*16+d] + w2*base[s2*16+d] + w3*base[s3*16+d]) * rs;
  size_t oi = ((size_t)b*1000 + s)*128 + hd*16 + d;
  unsigned short h = f2bf_rne(o);
  aoh[oi] = h;
  aol[oi] = f2bf_rne(o - bf2f(h));
}

// ---------------- PKM prep: M[k, (h,p,n)] ----------------
__global__ __launch_bounds__(256) void pkm_m_kernel(
    const float* __restrict__ Wq, const float* __restrict__ keys,
    float* __restrict__ M) {
  int hp = blockIdx.x;
  int h = hp >> 1, p = hp & 1;
  int tid = threadIdx.x;
  __shared__ float Ks[128][65];
  for (int e = tid; e < 8192; e += 256) {
    int n = e >> 6, d = e & 63;
    Ks[n][d] = keys[((size_t)(h*128 + n)*2 + p)*64 + d];
  }
  __syncthreads();
  int k = tid >> 1;
  int nbase = (tid & 1) * 64;
  float wk[64];
  const float* wq = Wq + (size_t)k*512 + h*128 + p*64;
  #pragma unroll
  for (int d = 0; d < 64; ++d) wk[d] = wq[d];
  for (int n = 0; n < 64; ++n) {
    int nn = nbase + n;
    float acc = 0.f;
    #pragma unroll
    for (int d = 0; d < 64; ++d) acc += wk[d]*Ks[nn][d];
    M[(size_t)k*1024 + hp*128 + nn] = acc;
  }
}

// ---------------- PKM select: ballot-bisection top-16 ----------------
__device__ inline unsigned long long pk_key(float v, int idx) {
  unsigned u = __float_as_uint(v);
  u = (u & 0x80000000u) ? ~u : (u | 0x80000000u);
  unsigned kv = ~u;
  return ((unsigned long long)kv << 32) | (unsigned)idx;
}
__device__ inline float pk_val(unsigned long long key) {
  unsigned m = ~(unsigned)(key >> 32);
  return (m & 0x80000000u) ? __uint_as_float(m & 0x7FFFFFFFu) : __uint_as_float(~m);
}
__device__ inline unsigned f32mono(float f) {
  unsigned u = __float_as_uint(f);
  return (u & 0x80000000u) ? ~u : (u | 0x80000000u);
}

__global__ __launch_bounds__(256) void pkm_select_kernel(
    const float* __restrict__ dots, const float* __restrict__ values,
    float* __restrict__ x2out) {
  int row = blockIdx.x;
  int tid = threadIdx.x;
  int h = tid >> 6;
  int lane = tid & 63;
  __shared__ unsigned long long STG[4][2][16];
  __shared__ float OUT[4][128];
  const float* dr = dots + (size_t)row*1024 + h*256;
  float vx0 = dr[lane], vx1 = dr[64 + lane];
  float vy0 = dr[128 + lane], vy1 = dr[192 + lane];
  unsigned mx0 = f32mono(vx0), mx1 = f32mono(vx1);
  unsigned my0 = f32mono(vy0), my1 = f32mono(vy1);
  unsigned long long below = ((1ull << lane) - 1ull);
  unsigned tx = 0, ty = 0;
  #pragma unroll
  for (int bit = 31; bit >= 0; --bit) {
    unsigned cx = tx | (1u << bit), cy = ty | (1u << bit);
    int nx = (int)(__popcll(__ballot(mx0 >= cx)) + __popcll(__ballot(mx1 >= cx)));
    int ny = (int)(__popcll(__ballot(my0 >= cy)) + __popcll(__ballot(my1 >= cy)));
    if (nx >= 16) tx = cx;
    if (ny >= 16) ty = cy;
  }
  {
    unsigned long long g0 = __ballot(mx0 > tx), g1 = __ballot(mx1 > tx);
    unsigned long long e0 = __ballot(mx0 == tx), e1 = __ballot(mx1 == tx);
    int nGT = (int)(__popcll(g0) + __popcll(g1));
    int need = 16 - nGT;
    if (mx0 > tx) {
      STG[h][0][(int)__popcll(g0 & below)] = pk_key(vx0, lane);
    } else if (mx0 == tx) {
      int er = (int)__popcll(e0 & below);
      if (er < need) STG[h][0][nGT + er] = pk_key(vx0, lane);
    }
    if (mx1 > tx) {
      STG[h][0][(int)(__popcll(g0) + __popcll(g1 & below))] = pk_key(vx1, 64 + lane);
    } else if (mx1 == tx) {
      int er = (int)(__popcll(e0) + __popcll(e1 & below));
      if (er < need) STG[h][0][nGT + er] = pk_key(vx1, 64 + lane);
    }
  }
  {
    unsigned long long g0 = __ballot(my0 > ty), g1 = __ballot(my1 > ty);
    unsigned long long e0 = __ballot(my0 == ty), e1 = __ballot(my1 == ty);
    int nGT = (int)(__popcll(g0) + __popcll(g1));
    int need = 16 - nGT;
    if (my0 > ty) {
      STG[h][1][(int)__popcll(g0 & below)] = pk_key(vy0, lane);
    } else if (my0 == ty) {
      int er = (int)__popcll(e0 & below);
      if (er < need) STG[h][1][nGT + er] = pk_key(vy0, lane);
    }
    if (my1 > ty) {
      STG[h][1][(int)(__popcll(g0) + __popcll(g1 & below))] = pk_key(vy1, 64 + lane);
    } else if (my1 == ty) {
      int er = (int)(__popcll(e0) + __popcll(e1 & below));
      if (er < need) STG[h][1][nGT + er] = pk_key(vy1, 64 + lane);
    }
  }
  unsigned long long skey = ~0ull;
  if (lane < 32) skey = STG[h][lane >> 4][lane & 15];
  int g16 = lane & 15;
  #pragma unroll
  for (int k = 2; k <= 16; k <<= 1) {
    #pragma unroll
    for (int j = k >> 1; j >= 1; j >>= 1) {
      unsigned long long pk2 = __shfl_xor(skey, j);
      bool low = ((g16 & j) == 0);
      bool up = ((g16 & k) == 0);
      bool take = (low == up) ? (pk2 < skey) : (pk2 > skey);
      if (take) skey = pk2;
    }
  }
  float sval = pk_val(skey);
  int sidx = (int)(unsigned)(skey & 0xFFFFFFFFull);
  int kx, ky;
  if      (lane < 16) { kx = 0; ky = lane; }
  else if (lane < 24) { kx = 1; ky = lane - 16; }
  else if (lane < 29) { kx = 2; ky = lane - 24; }
  else if (lane < 33) { kx = 3; ky = lane - 29; }
  else if (lane < 36) { kx = 4; ky = lane - 33; }
  else if (lane < 38) { kx = 5; ky = lane - 36; }
  else if (lane < 40) { kx = 6; ky = lane - 38; }
  else if (lane < 42) { kx = 7; ky = lane - 40; }
  else                { kx = 8 + (lane - 42); ky = 0; }
  float cval = __shfl(sval, kx) + __shfl(sval, 16 + ky);
  int cidx = kx*16 + ky;
  unsigned mc = (lane < 50) ? f32mono(cval) : 0u;
  unsigned tc = 0;
  #pragma unroll
  for (int bit = 31; bit >= 0; --bit) {
    unsigned c = tc | (1u << bit);
    if ((int)__popcll(__ballot(mc >= c)) >= 16) tc = c;
  }
  {
    unsigned long long gt = __ballot(mc > tc), eq = __ballot(mc == tc);
    int nGT = (int)__popcll(gt);
    int need = 16 - nGT;
    if (mc > tc) {
      STG[h][0][(int)__popcll(gt & below)] = pk_key(cval, cidx);
    } else if (lane < 50 && mc == tc) {
      int er = (int)__popcll(eq & below);
      if (er < need) STG[h][0][nGT + er] = pk_key(cval, cidx);
    }
  }
  unsigned long long ck = (lane < 16) ? STG[h][0][lane] : ~0ull;
  #pragma unroll
  for (int k = 2; k <= 16; k <<= 1) {
    #pragma unroll
    for (int j = k >> 1; j >= 1; j >>= 1) {
      unsigned long long pk2 = __shfl_xor(ck, j);
      bool low = ((g16 & j) == 0);
      bool up = ((g16 & k) == 0);
      bool take = (low == up) ? (pk2 < ck) : (pk2 > ck);
      if (take) ck = pk2;
    }
  }
  float myv = pk_val(ck);
  int pos = (int)(ck & 0xFFull);
  int ix = __shfl(sidx, pos >> 4);
  int iy = __shfl(sidx, 16 + (pos & 15));
  int myfi = ix*128 + iy;
  float fs0 = __shfl(myv, 0);
  float osum0 = 0.f, osum1 = 0.f, wsum = 0.f;
  #pragma unroll
  for (int k = 0; k < 16; ++k) {
    float fv = __shfl(myv, k);
    int fik = __shfl(myfi, k);
    float wgk = expf(fv - fs0);
    wsum += wgk;
    const float* vr = values + (size_t)fik * 128;
    osum0 += wgk * vr[lane];
    osum1 += wgk * vr[lane + 64];
  }
  float rs = 1.f / wsum;
  OUT[h][lane] = osum0 * rs;
  OUT[h][lane + 64] = osum1 * rs;
  __syncthreads();
  if (tid < 128) {
    float r = OUT[0][tid] + OUT[1][tid] + OUT[2][tid] + OUT[3][tid];
    x2out[(size_t)row*128 + tid] += r;
  }
}

// ---------------- host ----------------
extern "C" void kernel_launch(void* const* d_in, const int* in_sizes, int n_in,
                              void* d_out, int out_size, void* d_ws, size_t ws_size,
                              hipStream_t stream) {
  (void)in_sizes; (void)n_in; (void)out_size; (void)ws_size;
  const int* x_mcc  = (const int*)d_in[0];
  const int* x_amt  = (const int*)d_in[1];
  const int* x_hour = (const int*)d_in[2];
  const int* x_wday = (const int*)d_in[3];
  const float* emb_mcc  = (const float*)d_in[4];
  const float* emb_amt  = (const float*)d_in[5];
  const float* emb_hour = (const float*)d_in[6];
  const float* emb_wday = (const float*)d_in[7];
  const float* rot   = (const float*)d_in[8];
  const float* ln1_g = (const float*)d_in[9];
  const float* ln1_b = (const float*)d_in[10];
  const float* ln2_g = (const float*)d_in[11];
  const float* ln2_b = (const float*)d_in[12];
  const float* Wqk = (const float*)d_in[13];
  const float* Wv  = (const float*)d_in[14];
  const float* Wo  = (const float*)d_in[15];
  const float* bo  = (const float*)d_in[16];
  const float* ff_w1 = (const float*)d_in[17];
  const float* ff_b1 = (const float*)d_in[18];
  const float* ff_w2 = (const float*)d_in[19];
  const float* ff_b2 = (const float*)d_in[20];
  const float* pkm_wq   = (const float*)d_in[21];
  const float* pkm_keys = (const float*)d_in[22];
  const float* pkm_vals = (const float*)d_in[23];
  const float* norm_g = (const float*)d_in[24];
  const float* norm_b = (const float*)d_in[25];
  const float* hw1 = (const float*)d_in[26];
  const float* hb1 = (const float*)d_in[27];

  float* ws = (float*)d_ws;
  float* x1v  = ws;
  float* x2v  = ws + 2048000;
  float* hbuf = ws + 4096000;              // final-ln bf16 hi/lo
  float* scrA = ws + 6144000;
  float* qk     = scrA;
  float* vv     = scrA + 2048000;
  float* so     = scrA + 4096000;
  float* slse   = scrA + 12288000;
  int*   buckets= (int*)(scrA + 12800000);
  int*   stp    = (int*)(scrA + 13312000);
  int*   undo   = (int*)(scrA + 13824000);
  float* attn_o = scrA + 14336000;
  float* dotsb  = scrA;
  float* Mbuf   = ws + 22528000;

  unsigned short* hbuf_h = (unsigned short*)hbuf;
  unsigned short* hbuf_l = hbuf_h + 2048000;
  unsigned short* ao_h = (unsigned short*)attn_o;
  unsigned short* ao_l = ao_h + 2048000;
  unsigned short* big_h = (unsigned short*)scrA;     // [16000][512] (attn scratch dead)
  unsigned short* big_l = big_h + 8192000;

  unsigned short* wsp = (unsigned short*)(ws + 22700000);
  unsigned short* WqkvT_h = wsp;              // 8 x [256][128]
  unsigned short* WqkvT_l = wsp + 262144;
  unsigned short* WoT_h  = wsp + 524288;
  unsigned short* WoT_l  = wsp + 655360;
  unsigned short* f1T_h  = wsp + 786432;      // 6 x [512][128], 65536 each
  unsigned short* f1T_l  = wsp + 1179648;
  unsigned short* f2T_h  = wsp + 1572864;     // 6 x [128][512], 65536 each
  unsigned short* f2T_l  = wsp + 1966080;
  unsigned short* MT_h   = wsp + 2359296;     // [1024][128]
  unsigned short* MT_l   = wsp + 2490368;
  unsigned short* hw1T_h = wsp + 2621440;     // stacked [512][128]
  unsigned short* hw1T_l = wsp + 2686976;
  unsigned short* h2T_h  = wsp + 2752512;
  unsigned short* h2T_l  = wsp + 2814336;

  // ---- one-time weight splits ----
  { dim3 g(2,2,8); splitT_kernel<<<g,256,0,stream>>>(Wqk, WqkvT_h, WqkvT_l, 128,128, 16384, 32768); }
  { dim3 g(2,2,8); splitT_kernel<<<g,256,0,stream>>>(Wv,  WqkvT_h + 16384, WqkvT_l + 16384, 128,128, 16384, 32768); }
  { dim3 g(2,2,8); splitT_kernel<<<g,256,0,stream>>>(Wo,  WoT_h,  WoT_l,  128,128, 16384,16384); }
  { dim3 g(8,2,6); splitT_kernel<<<g,256,0,stream>>>(ff_w1, f1T_h, f1T_l, 128,512, 65536,65536); }
  { dim3 g(2,8,6); splitT_kernel<<<g,256,0,stream>>>(ff_w2, f2T_h, f2T_l, 512,128, 65536,65536); }
  { dim3 g(2,2,4); splitT_kernel<<<g,256,0,stream>>>(hw1, hw1T_h, hw1T_l, 128,128, 16384,16384); }
  const float* w2s[4] = {(const float*)d_in[28], (const float*)d_in[30], (const float*)d_in[32], (const float*)d_in[34]};
  const float* b2s[4] = {(const float*)d_in[29], (const float*)d_in[31], (const float*)d_in[33], (const float*)d_in[35]};
  const int ns[4] = {350, 100, 25, 8};
  const long h2off[4] = {0, 44800, 57600, 60800};
  for (int i = 0; i < 4; ++i) {
    dim3 g((ns[i]+63)/64, 2, 1);
    splitT_kernel<<<g,256,0,stream>>>(w2s[i], h2T_h + h2off[i], h2T_l + h2off[i], 128, ns[i], 0, 0);
  }

  embed_kernel<<<16000, 128, 0, stream>>>(x_mcc, x_amt, x_hour, x_wday,
      emb_mcc, emb_amt, emb_hour, emb_wday, x1v, x2v);

  int ffi = 0, pki = 0;
  for (int l = 0; l < 8; ++l) {
    // qkv: fused LN + [qk|vv] matmul
    { dim3 g(250, 4); mm_bf16_kernel<<<g, 256, 0, stream>>>(nullptr, nullptr, x2v, ln1_g + l*128, ln1_b + l*128,
        WqkvT_h + l*32768, WqkvT_l + l*32768, nullptr, qk, nullptr, nullptr, 16000, 256, 128, 128, MM_SPLIT|MM_LNA); }
    bucket_kernel<<<500, 256, 0, stream>>>(qk, rot, buckets);
    sort_kernel<<<512, 64, 0, stream>>>(buckets, stp, undo);
    attn_chunk_kernel<<<20480, 64, 0, stream>>>(qk, vv, stp, x_mcc, so, slse);
    combine_kernel<<<8000, 256, 0, stream>>>(so, slse, undo, ao_h, ao_l);
    { dim3 g(250, 2); mm_bf16_kernel<<<g, 256, 0, stream>>>(ao_h, ao_l, nullptr, nullptr, nullptr,
        WoT_h + l*16384, WoT_l + l*16384, bo + l*128, x1v, nullptr, nullptr, 16000, 128, 128, 128, MM_RES); }
    if (l == 3 || l == 6) {
      pkm_m_kernel<<<8, 256, 0, stream>>>(pkm_wq + (size_t)pki*65536, pkm_keys + (size_t)pki*65536, Mbuf);
      { dim3 g(16, 2, 1); splitT_kernel<<<g,256,0,stream>>>(Mbuf, MT_h, MT_l, 128, 1024, 0, 0); }
      { dim3 g(250, 16); mm_bf16_kernel<<<g, 256, 0, stream>>>(nullptr, nullptr, x1v, ln2_g + l*128, ln2_b + l*128,
          MT_h, MT_l, nullptr, dotsb, nullptr, nullptr, 16000, 1024, 128, 128, MM_LNA); }
      pkm_select_kernel<<<16000, 256, 0, stream>>>(dotsb, pkm_vals + (size_t)pki*2097152, x2v);
      ++pki;
    } else {
      { dim3 g(250, 8); mm_bf16_kernel<<<g, 256, 0, stream>>>(nullptr, nullptr, x1v, ln2_g + l*128, ln2_b + l*128,
          f1T_h + ffi*65536, f1T_l + ffi*65536, ff_b1 + ffi*512, nullptr, big_h, big_l, 16000, 512, 128, 128, MM_GELU|MM_SPLITONLY|MM_LNA); }
      { dim3 g(250, 2); mm_bf16_kernel<<<g, 256, 0, stream>>>(big_h, big_l, nullptr, nullptr, nullptr,
          f2T_h + ffi*65536, f2T_l + ffi*65536, ff_b2 + ffi*128, x2v, nullptr, nullptr, 16000, 128, 512, 512, MM_RES); }
      ++ffi;
    }
  }
  ln_kernel<<<4000, 256, 0, stream>>>(x1v, x2v, norm_g, norm_b, hbuf_h, hbuf_l);

  float* out = (float*)d_out;
  // batched head hidden: one [16000,512] = gelu(hbuf @ hw1_stacked + hb1)
  { dim3 g(250, 8); mm_bf16_kernel<<<g, 256, 0, stream>>>(hbuf_h, hbuf_l, nullptr, nullptr, nullptr,
      hw1T_h, hw1T_l, hb1, nullptr, big_h, big_l, 16000, 512, 128, 128, MM_GELU|MM_SPLITONLY); }
  size_t ooff = 0;
  for (int i = 0; i < 4; ++i) {
    { dim3 g(250, (unsigned)((ns[i]+63)/64)); mm_bf16_kernel<<<g, 256, 0, stream>>>(big_h + i*128, big_l + i*128,
        nullptr, nullptr, nullptr, h2T_h + h2off[i], h2T_l + h2off[i], b2s[i], out + ooff, nullptr, nullptr,
        16000, ns[i], 128, 512, 0); }
    ooff += (size_t)16000 * ns[i];
  }
}